// Round 9
// baseline (319.705 us; speedup 1.0000x reference)
//
#include <hip/hip_runtime.h>
#include <hip/hip_bf16.h>

// ---- problem constants ----
#define NW 5
#define KS 5
#define SEQ 196
#define DIM 384
#define NSUP 25        // NW*KS support images
#define NQRY 75        // query images
#define NIMG 100       // NSUP + NQRY
#define LSUP 4900      // NSUP*SEQ support rows
#define LSUP_PAD 4992  // 39*128, zero-padded K rows
#define QROWS 208      // padded qs rows per image (13*16)
#define BLOCK_W 980    // KS*SEQ rows per class block
#define OPT_STEPS 15
#define MTILES 39      // LSUP_PAD / MT
#define NSUPWG (NSUP * MTILES)   // 975 support GEMM blocks
#define NQWG   (NQRY * MTILES)   // 2925 query GEMM blocks
#define SPIN_LIMIT (1u << 22)    // hang-proofing: ~0.5s worst case, then give up

static constexpr float TEMP_F = 0.0510310363f;
static constexpr float INV_T  = 1.0f / TEMP_F;   // ~19.5959
static constexpr float LR_F   = 0.1f;

typedef short v8s __attribute__((ext_vector_type(8)));   // 8 x bf16 frag (4 VGPRs)
typedef float v4f __attribute__((ext_vector_type(4)));   // 4 x f32 acc

__device__ inline unsigned short f2bf(float x) {
    unsigned int u = __float_as_uint(x);
    u += 0x7fffu + ((u >> 16) & 1u);
    return (unsigned short)(u >> 16);
}

// agent-scope ops execute at the fabric coherence point (cross-XCD correct).
// RMW reads (fetch_add 0) are guaranteed-fresh there.
__device__ __forceinline__ float fresh_f32(float* p) {
    return __hip_atomic_fetch_add(p, 0.0f, __ATOMIC_RELAXED, __HIP_MEMORY_SCOPE_AGENT);
}
__device__ __forceinline__ int fresh_i32(int* p) {
    return __hip_atomic_fetch_add(p, 0, __ATOMIC_RELAXED, __HIP_MEMORY_SCOPE_AGENT);
}
__device__ __forceinline__ unsigned fresh_u32(unsigned* p) {
    return __hip_atomic_fetch_add(p, 0u, __ATOMIC_RELAXED, __HIP_MEMORY_SCOPE_AGENT);
}
__device__ __forceinline__ void agent_store_f32(float* p, float v) {
    __hip_atomic_store(p, v, __ATOMIC_RELAXED, __HIP_MEMORY_SCOPE_AGENT);
}
__device__ __forceinline__ void agent_store_i32(int* p, int v) {
    __hip_atomic_store(p, v, __ATOMIC_RELAXED, __HIP_MEMORY_SCOPE_AGENT);
}

// ---------------------------------------------------------------------------
// Kernel 1: fused normalize. Wave-per-row.
// ---------------------------------------------------------------------------
__global__ __launch_bounds__(256) void norm_all(const float* __restrict__ supk,
                                                const float* __restrict__ supq,
                                                const float* __restrict__ qry,
                                                unsigned short* __restrict__ Kb,
                                                unsigned short* __restrict__ Qall) {
    int R = blockIdx.x * 4 + (threadIdx.x >> 6);
    int l = threadIdx.x & 63;
    unsigned short* out;
    const float* in;
    float scale;
    if (R < LSUP_PAD) {
        out = Kb + (size_t)R * DIM;
        if (R >= LSUP) {
            #pragma unroll
            for (int k = 0; k < 6; ++k) out[l + 64 * k] = 0;
            return;
        }
        in = supk + (size_t)R * DIM;
        scale = INV_T;
    } else {
        int i = R - LSUP_PAD;
        int img = i / QROWS;
        int r = i - img * QROWS;
        out = Qall + (size_t)i * DIM;
        if (r >= SEQ) {
            #pragma unroll
            for (int k = 0; k < 6; ++k) out[l + 64 * k] = 0;
            return;
        }
        in = (img < NSUP)
            ? supq + ((size_t)img * SEQ + r) * DIM
            : qry  + ((size_t)(img - NSUP) * SEQ + r) * DIM;
        scale = 1.0f;
    }
    float x[6];
    #pragma unroll
    for (int k = 0; k < 6; ++k) x[k] = in[l + 64 * k];
    float s = 0.f;
    #pragma unroll
    for (int k = 0; k < 6; ++k) s += x[k] * x[k];
    #pragma unroll
    for (int m = 1; m < 64; m <<= 1) s += __shfl_xor(s, m);
    float sc = scale / fmaxf(sqrtf(s), 1e-8f);
    #pragma unroll
    for (int k = 0; k < 6; ++k) out[l + 64 * k] = f2bf(x[k] * sc);
}

// ---------------------------------------------------------------------------
// GEMM body: MFMA fused exp-sum, global_load_lds + XOR swizzle, XCD remap.
// R is written via agent-scope (sc1) stores so co-resident opt blocks can
// read it; each block bumps its phase counter after the drain.
// ---------------------------------------------------------------------------
#define MT  128
#define NTP 208
#define KCC 64

__device__ __forceinline__ void gload16(const void* g, void* l) {
    __builtin_amdgcn_global_load_lds(
        (__attribute__((address_space(1))) void*)g,
        (__attribute__((address_space(3))) void*)l, 16, 0, 0);
}

template<int IMG_BASE, int NWG>
__device__ __forceinline__ void gemm_body(
    int gid,
    const unsigned short* __restrict__ Kb,     // [4992][384] bf16, pre /T
    const unsigned short* __restrict__ Qall,   // [100][208][384] bf16
    float* __restrict__ Rall,
    unsigned* counter,
    unsigned short* Asm, unsigned short* Bsm)
{
    int t = threadIdx.x;

    // bijective XCD-aware remap (m204)
    constexpr int qq = NWG >> 3;
    constexpr int rr = NWG & 7;
    int xcd = gid & 7;
    int sub = gid >> 3;
    int L = (xcd < rr ? xcd * (qq + 1) : rr * (qq + 1) + (xcd - rr) * qq) + sub;
    int img = IMG_BASE + L / MTILES;
    int m_base = (L % MTILES) * MT;

    const unsigned short* Qimg = Qall + (size_t)img * (QROWS * DIM);

    int wv = t >> 6;        // wave 0..3
    int l  = t & 63;
    int lo = l & 15;        // MFMA frag row/col index
    int hi = l >> 4;        // k-group
    int mh = (wv >> 1) * 64;   // M-half base row
    int nh = wv & 1;           // N-half

    int srow = l >> 3;
    int skp  = (l & 7) ^ srow;      // involution within 8-slot row
    const unsigned short* aSrc = Kb   + (size_t)(m_base + wv * 32 + srow) * DIM + skp * 8;
    const unsigned short* bSrc = Qimg + (size_t)srow * DIM + skp * 8;

    v4f acc[4][7];
    #pragma unroll
    for (int m = 0; m < 4; ++m)
        #pragma unroll
        for (int n = 0; n < 7; ++n)
            acc[m][n] = (v4f){0.f, 0.f, 0.f, 0.f};

    for (int kb = 0; kb < DIM; kb += KCC) {
        #pragma unroll
        for (int j = 0; j < 4; ++j)
            gload16(aSrc + (size_t)j * 8 * DIM + kb,
                    Asm + (wv * 32 + j * 8) * KCC);
        #pragma unroll
        for (int jj = 0; jj < 7; ++jj) {
            int j = wv + jj * 4;
            if (j < 26)
                gload16(bSrc + (size_t)j * 8 * DIM + kb,
                        Bsm + j * 8 * KCC);
        }
        __syncthreads();   // drains vmcnt before LDS reads

        const unsigned short* Ar = Asm + (mh + lo) * KCC;
        const unsigned short* Br = Bsm + (nh * 112 + lo) * KCC;
        #pragma unroll
        for (int kk = 0; kk < 2; ++kk) {
            int koff = ((hi + 4 * kk) ^ (lo & 7)) * 8;   // swizzled k-slot
            v8s a0 = *(const v8s*)(Ar + koff);
            v8s a1 = *(const v8s*)(Ar + 16 * KCC + koff);
            v8s a2 = *(const v8s*)(Ar + 32 * KCC + koff);
            v8s a3 = *(const v8s*)(Ar + 48 * KCC + koff);
            #pragma unroll
            for (int n = 0; n < 7; ++n) {
                if (nh == 0 || n < 6) {   // wave-uniform
                    v8s bb = *(const v8s*)(Br + n * 16 * KCC + koff);
                    acc[0][n] = __builtin_amdgcn_mfma_f32_16x16x32_bf16(a0, bb, acc[0][n], 0, 0, 0);
                    acc[1][n] = __builtin_amdgcn_mfma_f32_16x16x32_bf16(a1, bb, acc[1][n], 0, 0, 0);
                    acc[2][n] = __builtin_amdgcn_mfma_f32_16x16x32_bf16(a2, bb, acc[2][n], 0, 0, 0);
                    acc[3][n] = __builtin_amdgcn_mfma_f32_16x16x32_bf16(a3, bb, acc[3][n], 0, 0, 0);
                }
            }
        }
        __syncthreads();
    }

    // epilogue: exp + per-wave column-half sums. C/D: col=lo, row=hi*4+reg.
    float s[4][4];
    #pragma unroll
    for (int m = 0; m < 4; ++m)
        #pragma unroll
        for (int j = 0; j < 4; ++j) s[m][j] = 0.f;
    #pragma unroll
    for (int n = 0; n < 7; ++n) {
        if (nh == 0 || n < 6) {
            bool ok = ((nh * 7 + n) * 16 + lo) < SEQ;
            #pragma unroll
            for (int m = 0; m < 4; ++m)
                #pragma unroll
                for (int j = 0; j < 4; ++j)
                    s[m][j] += ok ? __expf(acc[m][n][j]) : 0.f;
        }
    }
    #pragma unroll
    for (int mm = 1; mm < 16; mm <<= 1) {
        #pragma unroll
        for (int m = 0; m < 4; ++m)
            #pragma unroll
            for (int j = 0; j < 4; ++j)
                s[m][j] += __shfl_xor(s[m][j], mm);
    }
    float* rp = (float*)Asm;   // reuse A LDS: [2][128] row partials
    if (lo == 0) {
        #pragma unroll
        for (int m = 0; m < 4; ++m)
            #pragma unroll
            for (int j = 0; j < 4; ++j)
                rp[nh * 128 + mh + m * 16 + hi * 4 + j] = s[m][j];
    }
    __syncthreads();
    if (t < MT) {
        int gr = m_base + t;
        if (gr < LSUP) {
            float o = rp[t] + rp[128 + t];
            if (img < NSUP && (gr / SEQ) == img) o = 0.f;
            agent_store_f32(&Rall[(size_t)img * LSUP + gr], o);
        }
    }
    __syncthreads();   // vmcnt(0): sc1 stores acked at coherence point
    if (t == 0)
        __hip_atomic_fetch_add(counter, 1u, __ATOMIC_RELAXED, __HIP_MEMORY_SCOPE_AGENT);
}

// ---------------------------------------------------------------------------
// Kernel 2: MEGA kernel, 3905 blocks x 256.
// ids 0..4: optimizer (class w = id) + folded final prediction.
// ids 5..979: support GEMM. ids 980..3904: query GEMM.
// Exchange layout (contention-aware): Dbuf[step][w] is a 128B-padded
// 25-float column written by ONE producer; flags 128B apart; consumers read
// others' columns with one-shot RMWs, keep their own column in LDS.
// All spins are iteration-bounded (SPIN_LIMIT): a sync bug terminates with
// wrong-but-finite results instead of killing the container.
// ---------------------------------------------------------------------------
__global__ __launch_bounds__(256, 3) void mega(
    const unsigned short* __restrict__ Kb,
    const unsigned short* __restrict__ Qall,
    float* __restrict__ Rall,
    const int* __restrict__ labels,
    float* __restrict__ Dbuf,       // [16][5][32] floats, pre-zeroed
    int* __restrict__ flags,        // [5*32] ints, pre-zeroed
    unsigned* __restrict__ sdone,   // support-done counter, pre-zeroed
    unsigned* __restrict__ qdone,   // query-done counter, pre-zeroed
    float* __restrict__ out)        // [75][5]
{
    __shared__ __align__(16) unsigned short Asm[MT * KCC];
    __shared__ __align__(16) unsigned short Bsm[NTP * KCC];

    int id = blockIdx.x;
    if (id >= NW + NSUPWG) {
        gemm_body<NSUP, NQWG>(id - (NW + NSUPWG), Kb, Qall, Rall, qdone, Asm, Bsm);
        return;
    }
    if (id >= NW) {
        gemm_body<0, NSUPWG>(id - NW, Kb, Qall, Rall, sdone, Asm, Bsm);
        return;
    }

    // ---- optimizer block for class w ----
    float* sh  = (float*)Asm;
    float* red = sh;              // [4][25]
    float* cfs = sh + 100;        // [25]
    float* Dsm = sh + 128;        // [125]
    float* myD = sh + 256;        // [25]
    int*   lsm = (int*)(sh + 288);// [25]
    float* esm = (float*)Bsm;     // [980]

    int w = id;
    int t = threadIdx.x;
    int wave = t >> 6, lane = t & 63;

    // wait for all 975 support blocks (agent RMW; one-time; bounded)
    if (t == 0) {
        unsigned spins = 0;
        while (fresh_u32(sdone) < (unsigned)NSUPWG && ++spins < SPIN_LIMIT)
            __builtin_amdgcn_s_sleep(8);
    }
    __syncthreads();

    // rows r = t + 256k, k<4 (k=3 valid only for t<212); inactive rows -> 0.
    float Rv[4][NSUP];
    #pragma unroll
    for (int b = 0; b < NSUP; ++b) {
        const float* Rb = Rall + (size_t)b * LSUP + w * BLOCK_W;
        Rv[0][b] = Rb[t];
        Rv[1][b] = Rb[t + 256];
        Rv[2][b] = Rb[t + 512];
        Rv[3][b] = (t < BLOCK_W - 768) ? Rb[t + 768] : 0.f;
    }
    if (t < NSUP) lsm[t] = labels[t];

    float e0 = 1.f, e1 = 1.f, e2 = 1.f, e3 = 1.f;
    float v0 = 0.f, v1 = 0.f, v2 = 0.f, v3 = 0.f;

    auto pushD = [&](int step) {
        float part[NSUP];
        #pragma unroll
        for (int b = 0; b < NSUP; ++b)
            part[b] = e0 * Rv[0][b] + e1 * Rv[1][b] + e2 * Rv[2][b] + e3 * Rv[3][b];
        #pragma unroll
        for (int b = 0; b < NSUP; ++b) {
            #pragma unroll
            for (int m = 32; m; m >>= 1) part[b] += __shfl_xor(part[b], m);
        }
        if (lane == 0) {
            #pragma unroll
            for (int b = 0; b < NSUP; ++b) red[wave * NSUP + b] = part[b];
        }
        __syncthreads();
        if (t < NSUP) {
            float s = red[t] + red[NSUP + t] + red[2 * NSUP + t] + red[3 * NSUP + t];
            myD[t] = s;                                    // LDS self-copy
            agent_store_f32(&Dbuf[(step * NW + w) * 32 + t], s);
        }
        __syncthreads();   // vmcnt(0) drain: payload acked at coherence point
        if (t == 0)
            agent_store_i32(&flags[w * 32], step + 1);
    };

    pushD(0);    // e = 1

    for (int s = 0; s < OPT_STEPS; ++s) {
        // wait for all 5 blocks' step-s D: 5 poller lanes, 128B-spread flags
        if (wave == 0) {
            unsigned spins = 0;
            for (;;) {
                int f = (lane < NW) ? fresh_i32(&flags[lane * 32]) : 0x7fffffff;
                if (__all(f >= s + 1)) break;
                if (++spins >= SPIN_LIMIT) break;
                __builtin_amdgcn_s_sleep(1);
            }
        }
        __syncthreads();
        if (t < 125) {
            int wp = t / 25, b = t - wp * 25;
            float dv = (wp == w) ? myD[b]
                                 : fresh_f32(&Dbuf[(s * NW + wp) * 32 + b]);
            Dsm[b * 5 + wp] = dv;
        }
        __syncthreads();
        if (t < NSUP) {
            float Dsum = 0.f, Dw = 1.f;
            #pragma unroll
            for (int ww = 0; ww < NW; ++ww) {
                float d = Dsm[t * 5 + ww];
                Dsum += d;
                if (ww == w) Dw = d;
            }
            cfs[t] = ((Dw / Dsum) - (w == lsm[t] ? 1.f : 0.f)) * (INV_T / 25.f) / Dw;
        }
        __syncthreads();
        float g0 = 0.f, g1 = 0.f, g2 = 0.f, g3 = 0.f;
        #pragma unroll
        for (int b = 0; b < NSUP; ++b) {
            float c = cfs[b];
            g0 += c * Rv[0][b];
            g1 += c * Rv[1][b];
            g2 += c * Rv[2][b];
            g3 += c * Rv[3][b];
        }
        v0 -= LR_F * e0 * g0; e0 = __expf(v0 * INV_T);
        v1 -= LR_F * e1 * g1; e1 = __expf(v1 * INV_T);
        v2 -= LR_F * e2 * g2; e2 = __expf(v2 * INV_T);
        v3 -= LR_F * e3 * g3; e3 = __expf(v3 * INV_T);
        __syncthreads();      // red/Dsm/cfs reuse protection
        if (s + 1 < OPT_STEPS) pushD(s + 1);
    }

    // ---- folded final prediction ----
    esm[t] = e0;
    esm[t + 256] = e1;
    esm[t + 512] = e2;
    if (t < BLOCK_W - 768) esm[t + 768] = e3;
    if (t == 0) {   // wait for query R (sc1-written + counted; bounded)
        unsigned spins = 0;
        while (fresh_u32(qdone) < (unsigned)NQWG && ++spins < SPIN_LIMIT)
            __builtin_amdgcn_s_sleep(8);
    }
    __syncthreads();
    for (int qb = wave; qb < NQRY; qb += 4) {
        const float* R = Rall + (size_t)(NSUP + qb) * LSUP + w * BLOCK_W;
        float p = 0.f;
        for (int i = lane; i < BLOCK_W; i += 64) p += esm[i] * R[i];
        #pragma unroll
        for (int m = 32; m; m >>= 1) p += __shfl_xor(p, m);
        if (lane == 0) out[qb * 5 + w] = logf(p);
    }
}

// ---------------------------------------------------------------------------
extern "C" void kernel_launch(void* const* d_in, const int* in_sizes, int n_in,
                              void* d_out, int out_size, void* d_ws, size_t ws_size,
                              hipStream_t stream) {
    const float* sup_key = (const float*)d_in[0];   // [25,196,384]
    const float* sup_qry = (const float*)d_in[1];   // [25,196,384]
    const float* qry     = (const float*)d_in[2];   // [75,196,384]
    const int*   labels  = (const int*)d_in[3];     // [25]
    float* out = (float*)d_out;                     // [75,5]

    char* ws = (char*)d_ws;
    size_t off = 0;
    auto take = [&](size_t bytes) {
        char* p = ws + off;
        off = (off + bytes + 255) & ~(size_t)255;
        return p;
    };
    unsigned short* Kb   = (unsigned short*)take((size_t)LSUP_PAD * DIM * 2);
    unsigned short* Qall = (unsigned short*)take((size_t)NIMG * QROWS * DIM * 2);
    float*          Rall = (float*)take((size_t)NIMG * LSUP * 4);
    float*          Dbuf = (float*)take((size_t)16 * NW * 32 * 4);   // 10 KiB
    int*            fl   = (int*)take(256 * 4);
    int*            flags = fl;                     // [5*32]
    unsigned*       sdone = (unsigned*)(fl + 192);
    unsigned*       qdone = (unsigned*)(fl + 224);

    hipMemsetAsync(Dbuf, 0, (size_t)16 * NW * 32 * 4, stream);
    hipMemsetAsync(fl, 0, 256 * 4, stream);

    norm_all<<<(LSUP_PAD + NIMG * QROWS) / 4, 256, 0, stream>>>(
        sup_key, sup_qry, qry, Kb, Qall);

    mega<<<NW + NSUPWG + NQWG, 256, 0, stream>>>(
        Kb, Qall, Rall, labels, Dbuf, flags, sdone, qdone, out);
}

// Round 10
// 281.104 us; speedup vs baseline: 1.1373x; 1.1373x over previous
//
#include <hip/hip_runtime.h>
#include <hip/hip_bf16.h>

// ---- problem constants ----
#define NW 5
#define KS 5
#define SEQ 196
#define DIM 384
#define NSUP 25        // NW*KS support images
#define NQRY 75        // query images
#define NIMG 100       // NSUP + NQRY
#define LSUP 4900      // NSUP*SEQ support rows
#define LSUP_PAD 4992  // 39*128, zero-padded K rows
#define QROWS 208      // padded qs rows per image (13*16)
#define BLOCK_W 980    // KS*SEQ rows per class block
#define OPT_STEPS 15
#define MTILES 39      // LSUP_PAD / MT
#define NSUPWG (NSUP * MTILES)   // 975 support GEMM blocks
#define NQWG   (NQRY * MTILES)   // 2925 query GEMM blocks
#define SPIN_LIMIT (1u << 22)    // hang-proofing

static constexpr float TEMP_F = 0.0510310363f;
static constexpr float INV_T  = 1.0f / TEMP_F;   // ~19.5959
static constexpr float LR_F   = 0.1f;

typedef short v8s __attribute__((ext_vector_type(8)));   // 8 x bf16 frag (4 VGPRs)
typedef float v4f __attribute__((ext_vector_type(4)));   // 4 x f32 acc

__device__ inline unsigned short f2bf(float x) {
    unsigned int u = __float_as_uint(x);
    u += 0x7fffu + ((u >> 16) & 1u);
    return (unsigned short)(u >> 16);
}

// agent-scope ops execute at the fabric coherence point (cross-XCD correct).
// RMW reads (fetch_add 0) are guaranteed-fresh there.
__device__ __forceinline__ float fresh_f32(float* p) {
    return __hip_atomic_fetch_add(p, 0.0f, __ATOMIC_RELAXED, __HIP_MEMORY_SCOPE_AGENT);
}
__device__ __forceinline__ int fresh_i32(int* p) {
    return __hip_atomic_fetch_add(p, 0, __ATOMIC_RELAXED, __HIP_MEMORY_SCOPE_AGENT);
}
__device__ __forceinline__ unsigned fresh_u32(unsigned* p) {
    return __hip_atomic_fetch_add(p, 0u, __ATOMIC_RELAXED, __HIP_MEMORY_SCOPE_AGENT);
}
__device__ __forceinline__ void agent_store_f32(float* p, float v) {
    __hip_atomic_store(p, v, __ATOMIC_RELAXED, __HIP_MEMORY_SCOPE_AGENT);
}
__device__ __forceinline__ void agent_store_i32(int* p, int v) {
    __hip_atomic_store(p, v, __ATOMIC_RELAXED, __HIP_MEMORY_SCOPE_AGENT);
}

// ---------------------------------------------------------------------------
// Kernel 1: fused normalize. Wave-per-row.
// ---------------------------------------------------------------------------
__global__ __launch_bounds__(256) void norm_all(const float* __restrict__ supk,
                                                const float* __restrict__ supq,
                                                const float* __restrict__ qry,
                                                unsigned short* __restrict__ Kb,
                                                unsigned short* __restrict__ Qall) {
    int R = blockIdx.x * 4 + (threadIdx.x >> 6);
    int l = threadIdx.x & 63;
    unsigned short* out;
    const float* in;
    float scale;
    if (R < LSUP_PAD) {
        out = Kb + (size_t)R * DIM;
        if (R >= LSUP) {
            #pragma unroll
            for (int k = 0; k < 6; ++k) out[l + 64 * k] = 0;
            return;
        }
        in = supk + (size_t)R * DIM;
        scale = INV_T;
    } else {
        int i = R - LSUP_PAD;
        int img = i / QROWS;
        int r = i - img * QROWS;
        out = Qall + (size_t)i * DIM;
        if (r >= SEQ) {
            #pragma unroll
            for (int k = 0; k < 6; ++k) out[l + 64 * k] = 0;
            return;
        }
        in = (img < NSUP)
            ? supq + ((size_t)img * SEQ + r) * DIM
            : qry  + ((size_t)(img - NSUP) * SEQ + r) * DIM;
        scale = 1.0f;
    }
    float x[6];
    #pragma unroll
    for (int k = 0; k < 6; ++k) x[k] = in[l + 64 * k];
    float s = 0.f;
    #pragma unroll
    for (int k = 0; k < 6; ++k) s += x[k] * x[k];
    #pragma unroll
    for (int m = 1; m < 64; m <<= 1) s += __shfl_xor(s, m);
    float sc = scale / fmaxf(sqrtf(s), 1e-8f);
    #pragma unroll
    for (int k = 0; k < 6; ++k) out[l + 64 * k] = f2bf(x[k] * sc);
}

// ---------------------------------------------------------------------------
// GEMM body: MFMA fused exp-sum. Double-buffered KCC=32 2-phase pipeline:
// per step, issue next-step global_load_lds into buf^1, compute from buf,
// single __syncthreads (its vmcnt(0) drain lands the overlapped stage).
// LDS swizzle for 64B rows: slot' = slot ^ ((row>>1)&3), applied on the
// pre-swizzled global source AND the ds_read address (rule #21); bank-walk
// verified conflict-free for lane-consecutive ds_read_b128 groups.
// SUPPORT blocks write R via agent-scope stores + bump sdone (opt blocks
// consume); QUERY blocks use plain stores (round-9 lesson: per-dword sc1
// write-through for 2925 blocks stretched the GEMM ~2x).
// ---------------------------------------------------------------------------
#define MT  128
#define NTP 208
#define KCC 32
#define NSTEP (DIM / KCC)   // 12

__device__ __forceinline__ void gload16(const void* g, void* l) {
    __builtin_amdgcn_global_load_lds(
        (__attribute__((address_space(1))) void*)g,
        (__attribute__((address_space(3))) void*)l, 16, 0, 0);
}

template<int IMG_BASE, int NWG, bool SUPPORT>
__device__ __forceinline__ void gemm_body(
    int gid,
    const unsigned short* __restrict__ Kb,     // [4992][384] bf16, pre /T
    const unsigned short* __restrict__ Qall,   // [100][208][384] bf16
    float* __restrict__ Rall,
    unsigned* counter,
    unsigned short* AsmB, unsigned short* BsmB)   // [2][MT*KCC], [2][NTP*KCC]
{
    int t = threadIdx.x;

    // bijective XCD-aware remap (m204)
    constexpr int qq = NWG >> 3;
    constexpr int rr = NWG & 7;
    int xcd = gid & 7;
    int sub = gid >> 3;
    int L = (xcd < rr ? xcd * (qq + 1) : rr * (qq + 1) + (xcd - rr) * qq) + sub;
    int img = IMG_BASE + L / MTILES;
    int m_base = (L % MTILES) * MT;

    const unsigned short* Qimg = Qall + (size_t)img * (QROWS * DIM);

    int wv = t >> 6;        // wave 0..3
    int l  = t & 63;
    int lo = l & 15;        // MFMA frag row/col index
    int hi = l >> 4;        // k-group (16B slot 0..3)
    int mh = (wv >> 1) * 64;   // M-half base row
    int nh = wv & 1;           // N-half

    // staging: one gload16 = 1024B = 16 rows x 64B, linear LDS dest.
    // lane l covers (row = l>>2, slot = l&3); source slot pre-swizzled by
    // c(row) = (row>>1)&3 = (l>>3)&3.
    int srow = l >> 2;
    int skp  = (l & 3) ^ ((l >> 3) & 3);
    const unsigned short* aSrc = Kb   + (size_t)(m_base + srow) * DIM + skp * 8;
    const unsigned short* bSrc = Qimg + (size_t)srow * DIM + skp * 8;

    auto stage = [&](int buf, int kb) {
        unsigned short* Ab = AsmB + buf * (MT * KCC);
        #pragma unroll
        for (int g2 = 0; g2 < 2; ++g2) {
            int g = wv * 2 + g2;        // 8 groups x 16 rows = 128
            gload16(aSrc + (size_t)g * 16 * DIM + kb, Ab + g * 16 * KCC);
        }
        unsigned short* Bb = BsmB + buf * (NTP * KCC);
        #pragma unroll
        for (int jj = 0; jj < 4; ++jj) {
            int g = wv + jj * 4;        // 13 groups x 16 rows = 208
            if (g < 13)
                gload16(bSrc + (size_t)g * 16 * DIM + kb, Bb + g * 16 * KCC);
        }
    };

    v4f acc[4][7];
    #pragma unroll
    for (int m = 0; m < 4; ++m)
        #pragma unroll
        for (int n = 0; n < 7; ++n)
            acc[m][n] = (v4f){0.f, 0.f, 0.f, 0.f};

    // read-side swizzled k-slot: rows read are mh+16m+lo / nh*112+16n+lo;
    // all base terms are 0 mod 8 -> c(row) = (lo>>1)&3 uniformly.
    int koff = (hi ^ ((lo >> 1) & 3)) * 8;

    stage(0, 0);
    __syncthreads();
    int cur = 0;
    for (int s = 0; s < NSTEP; ++s) {
        if (s + 1 < NSTEP) stage(cur ^ 1, (s + 1) * KCC);

        const unsigned short* Ar = AsmB + cur * (MT * KCC) + (mh + lo) * KCC + koff;
        const unsigned short* Br = BsmB + cur * (NTP * KCC) + (nh * 112 + lo) * KCC + koff;
        v8s a0 = *(const v8s*)(Ar);
        v8s a1 = *(const v8s*)(Ar + 16 * KCC);
        v8s a2 = *(const v8s*)(Ar + 32 * KCC);
        v8s a3 = *(const v8s*)(Ar + 48 * KCC);
        #pragma unroll
        for (int n = 0; n < 7; ++n) {
            if (nh == 0 || n < 6) {   // wave-uniform
                v8s bb = *(const v8s*)(Br + n * 16 * KCC);
                acc[0][n] = __builtin_amdgcn_mfma_f32_16x16x32_bf16(a0, bb, acc[0][n], 0, 0, 0);
                acc[1][n] = __builtin_amdgcn_mfma_f32_16x16x32_bf16(a1, bb, acc[1][n], 0, 0, 0);
                acc[2][n] = __builtin_amdgcn_mfma_f32_16x16x32_bf16(a2, bb, acc[2][n], 0, 0, 0);
                acc[3][n] = __builtin_amdgcn_mfma_f32_16x16x32_bf16(a3, bb, acc[3][n], 0, 0, 0);
            }
        }
        __syncthreads();   // vmcnt(0): stage s+1 landed; buf cur free to reuse
        cur ^= 1;
    }

    // epilogue: exp + per-wave column-half sums. C/D: col=lo, row=hi*4+reg.
    float s[4][4];
    #pragma unroll
    for (int m = 0; m < 4; ++m)
        #pragma unroll
        for (int j = 0; j < 4; ++j) s[m][j] = 0.f;
    #pragma unroll
    for (int n = 0; n < 7; ++n) {
        if (nh == 0 || n < 6) {
            bool ok = ((nh * 7 + n) * 16 + lo) < SEQ;
            #pragma unroll
            for (int m = 0; m < 4; ++m)
                #pragma unroll
                for (int j = 0; j < 4; ++j)
                    s[m][j] += ok ? __expf(acc[m][n][j]) : 0.f;
        }
    }
    #pragma unroll
    for (int mm = 1; mm < 16; mm <<= 1) {
        #pragma unroll
        for (int m = 0; m < 4; ++m)
            #pragma unroll
            for (int j = 0; j < 4; ++j)
                s[m][j] += __shfl_xor(s[m][j], mm);
    }
    float* rp = (float*)AsmB;   // reuse A LDS: [2][128] row partials
    if (lo == 0) {
        #pragma unroll
        for (int m = 0; m < 4; ++m)
            #pragma unroll
            for (int j = 0; j < 4; ++j)
                rp[nh * 128 + mh + m * 16 + hi * 4 + j] = s[m][j];
    }
    __syncthreads();
    if (t < MT) {
        int gr = m_base + t;
        if (gr < LSUP) {
            float o = rp[t] + rp[128 + t];
            if (img < NSUP && (gr / SEQ) == img) o = 0.f;
            if (SUPPORT)   // write-through so co-resident opt blocks see it
                agent_store_f32(&Rall[(size_t)img * LSUP + gr], o);
            else
                Rall[(size_t)img * LSUP + gr] = o;
        }
    }
    if (SUPPORT) {
        __syncthreads();   // vmcnt(0): sc1 stores acked at coherence point
        if (t == 0)
            __hip_atomic_fetch_add(counter, 1u, __ATOMIC_RELAXED, __HIP_MEMORY_SCOPE_AGENT);
    }
}

// ---------------------------------------------------------------------------
// Kernel 2: MEGA kernel, 3905 blocks x 256.
// ids 0..4: optimizer (class w = id). ids 5..979: support GEMM.
// ids 980..3904: query GEMM. D-exchange: per-producer 128B-padded columns,
// one-shot agent RMW reads, 5 poller lanes, all spins bounded.
// ---------------------------------------------------------------------------
__global__ __launch_bounds__(256, 3) void mega(
    const unsigned short* __restrict__ Kb,
    const unsigned short* __restrict__ Qall,
    float* __restrict__ Rall,
    const int* __restrict__ labels,
    float* __restrict__ Dbuf,       // [16][5][32] floats, pre-zeroed
    int* __restrict__ flags,        // [5*32] ints, pre-zeroed
    unsigned* __restrict__ sdone,   // support-done counter, pre-zeroed
    float* __restrict__ e_out)      // [4900] final e^{v/T}
{
    __shared__ __align__(16) unsigned short Asm[2][MT * KCC];    // 16 KiB
    __shared__ __align__(16) unsigned short Bsm[2][NTP * KCC];   // 26 KiB

    int id = blockIdx.x;
    if (id >= NW + NSUPWG) {
        gemm_body<NSUP, NQWG, false>(id - (NW + NSUPWG), Kb, Qall, Rall,
                                     sdone, &Asm[0][0], &Bsm[0][0]);
        return;
    }
    if (id >= NW) {
        gemm_body<0, NSUPWG, true>(id - NW, Kb, Qall, Rall,
                                   sdone, &Asm[0][0], &Bsm[0][0]);
        return;
    }

    // ---- optimizer block for class w ----
    float* sh  = (float*)Asm;
    float* red = sh;              // [4][25]
    float* cfs = sh + 100;        // [25]
    float* Dsm = sh + 128;        // [125]
    float* myD = sh + 256;        // [25]
    int*   lsm = (int*)(sh + 288);// [25]

    int w = id;
    int t = threadIdx.x;
    int wave = t >> 6, lane = t & 63;

    // wait for all 975 support blocks (agent RMW; one-time; bounded)
    if (t == 0) {
        unsigned spins = 0;
        while (fresh_u32(sdone) < (unsigned)NSUPWG && ++spins < SPIN_LIMIT)
            __builtin_amdgcn_s_sleep(8);
    }
    __syncthreads();

    // rows r = t + 256k, k<4 (k=3 valid only for t<212); inactive rows -> 0.
    float Rv[4][NSUP];
    #pragma unroll
    for (int b = 0; b < NSUP; ++b) {
        const float* Rb = Rall + (size_t)b * LSUP + w * BLOCK_W;
        Rv[0][b] = Rb[t];
        Rv[1][b] = Rb[t + 256];
        Rv[2][b] = Rb[t + 512];
        Rv[3][b] = (t < BLOCK_W - 768) ? Rb[t + 768] : 0.f;
    }
    if (t < NSUP) lsm[t] = labels[t];

    float e0 = 1.f, e1 = 1.f, e2 = 1.f, e3 = 1.f;
    float v0 = 0.f, v1 = 0.f, v2 = 0.f, v3 = 0.f;

    auto pushD = [&](int step) {
        float part[NSUP];
        #pragma unroll
        for (int b = 0; b < NSUP; ++b)
            part[b] = e0 * Rv[0][b] + e1 * Rv[1][b] + e2 * Rv[2][b] + e3 * Rv[3][b];
        #pragma unroll
        for (int b = 0; b < NSUP; ++b) {
            #pragma unroll
            for (int m = 32; m; m >>= 1) part[b] += __shfl_xor(part[b], m);
        }
        if (lane == 0) {
            #pragma unroll
            for (int b = 0; b < NSUP; ++b) red[wave * NSUP + b] = part[b];
        }
        __syncthreads();
        if (t < NSUP) {
            float s = red[t] + red[NSUP + t] + red[2 * NSUP + t] + red[3 * NSUP + t];
            myD[t] = s;                                    // LDS self-copy
            agent_store_f32(&Dbuf[(step * NW + w) * 32 + t], s);
        }
        __syncthreads();   // vmcnt(0) drain: payload acked at coherence point
        if (t == 0)
            agent_store_i32(&flags[w * 32], step + 1);
    };

    pushD(0);    // e = 1

    for (int s = 0; s < OPT_STEPS; ++s) {
        if (wave == 0) {
            unsigned spins = 0;
            for (;;) {
                int f = (lane < NW) ? fresh_i32(&flags[lane * 32]) : 0x7fffffff;
                if (__all(f >= s + 1)) break;
                if (++spins >= SPIN_LIMIT) break;
                __builtin_amdgcn_s_sleep(1);
            }
        }
        __syncthreads();
        if (t < 125) {
            int wp = t / 25, b = t - wp * 25;
            float dv = (wp == w) ? myD[b]
                                 : fresh_f32(&Dbuf[(s * NW + wp) * 32 + b]);
            Dsm[b * 5 + wp] = dv;
        }
        __syncthreads();
        if (t < NSUP) {
            float Dsum = 0.f, Dw = 1.f;
            #pragma unroll
            for (int ww = 0; ww < NW; ++ww) {
                float d = Dsm[t * 5 + ww];
                Dsum += d;
                if (ww == w) Dw = d;
            }
            cfs[t] = ((Dw / Dsum) - (w == lsm[t] ? 1.f : 0.f)) * (INV_T / 25.f) / Dw;
        }
        __syncthreads();
        float g0 = 0.f, g1 = 0.f, g2 = 0.f, g3 = 0.f;
        #pragma unroll
        for (int b = 0; b < NSUP; ++b) {
            float c = cfs[b];
            g0 += c * Rv[0][b];
            g1 += c * Rv[1][b];
            g2 += c * Rv[2][b];
            g3 += c * Rv[3][b];
        }
        v0 -= LR_F * e0 * g0; e0 = __expf(v0 * INV_T);
        v1 -= LR_F * e1 * g1; e1 = __expf(v1 * INV_T);
        v2 -= LR_F * e2 * g2; e2 = __expf(v2 * INV_T);
        v3 -= LR_F * e3 * g3; e3 = __expf(v3 * INV_T);
        __syncthreads();      // red/Dsm/cfs reuse protection
        if (s + 1 < OPT_STEPS) pushD(s + 1);
    }

    // export e (plain stores; kernel-end writeback covers final_pred)
    float* eo = e_out + w * BLOCK_W;
    eo[t]       = e0;
    eo[t + 256] = e1;
    eo[t + 512] = e2;
    if (t < BLOCK_W - 768) eo[t + 768] = e3;
}

// ---------------------------------------------------------------------------
// Kernel 3: final prediction. 375 blocks (qb*5+w) x 256.
// ---------------------------------------------------------------------------
__global__ __launch_bounds__(256) void final_pred(const float* __restrict__ Rall,
                                                  const float* __restrict__ e_out,
                                                  float* __restrict__ out) {
    __shared__ float ws[4];
    int blk = blockIdx.x;
    int qb = blk / 5, w = blk % 5;
    const float* R  = Rall + (size_t)(NSUP + qb) * LSUP + w * BLOCK_W;
    const float* eb = e_out + w * BLOCK_W;
    int t = threadIdx.x;
    float p = 0.f;
    for (int i = t; i < BLOCK_W; i += 256) p += eb[i] * R[i];
    #pragma unroll
    for (int m = 32; m; m >>= 1) p += __shfl_xor(p, m);
    if ((t & 63) == 0) ws[t >> 6] = p;
    __syncthreads();
    if (t == 0) out[blk] = logf(ws[0] + ws[1] + ws[2] + ws[3]);
}

// ---------------------------------------------------------------------------
extern "C" void kernel_launch(void* const* d_in, const int* in_sizes, int n_in,
                              void* d_out, int out_size, void* d_ws, size_t ws_size,
                              hipStream_t stream) {
    const float* sup_key = (const float*)d_in[0];   // [25,196,384]
    const float* sup_qry = (const float*)d_in[1];   // [25,196,384]
    const float* qry     = (const float*)d_in[2];   // [75,196,384]
    const int*   labels  = (const int*)d_in[3];     // [25]
    float* out = (float*)d_out;                     // [75,5]

    char* ws = (char*)d_ws;
    size_t off = 0;
    auto take = [&](size_t bytes) {
        char* p = ws + off;
        off = (off + bytes + 255) & ~(size_t)255;
        return p;
    };
    unsigned short* Kb   = (unsigned short*)take((size_t)LSUP_PAD * DIM * 2);
    unsigned short* Qall = (unsigned short*)take((size_t)NIMG * QROWS * DIM * 2);
    float*          Rall = (float*)take((size_t)NIMG * LSUP * 4);
    float*          Dbuf = (float*)take((size_t)16 * NW * 32 * 4);   // 10 KiB
    float*          eout = (float*)take((size_t)LSUP * 4);
    int*            fl   = (int*)take(256 * 4);
    int*            flags = fl;                     // [5*32]
    unsigned*       sdone = (unsigned*)(fl + 192);

    hipMemsetAsync(Dbuf, 0, (size_t)16 * NW * 32 * 4, stream);
    hipMemsetAsync(fl, 0, 256 * 4, stream);

    norm_all<<<(LSUP_PAD + NIMG * QROWS) / 4, 256, 0, stream>>>(
        sup_key, sup_qry, qry, Kb, Qall);

    mega<<<NW + NSUPWG + NQWG, 256, 0, stream>>>(
        Kb, Qall, Rall, labels, Dbuf, flags, sdone, eout);

    final_pred<<<NQRY * NW, 256, 0, stream>>>(Rall, eout, out);
}

// Round 11
// 237.167 us; speedup vs baseline: 1.3480x; 1.1853x over previous
//
#include <hip/hip_runtime.h>
#include <hip/hip_bf16.h>

// ---- problem constants ----
#define NW 5
#define KS 5
#define SEQ 196
#define DIM 384
#define NSUP 25        // NW*KS support images
#define NQRY 75        // query images
#define NIMG 100       // NSUP + NQRY
#define LSUP 4900      // NSUP*SEQ support rows
#define LSUP_PAD 4992  // 39*128, zero-padded K rows
#define QROWS 208      // padded qs rows per image (13*16)
#define BLOCK_W 980    // KS*SEQ rows per class block
#define OPT_STEPS 15
#define MTILES 39      // LSUP_PAD / MT
#define NSUPWG (NSUP * MTILES)   // 975 support GEMM blocks
#define NQWG   (NQRY * MTILES)   // 2925 query GEMM blocks
#define SPIN_LIMIT (1u << 22)    // hang-proofing

static constexpr float TEMP_F = 0.0510310363f;
static constexpr float INV_T  = 1.0f / TEMP_F;   // ~19.5959
static constexpr float LR_F   = 0.1f;

typedef short v8s __attribute__((ext_vector_type(8)));   // 8 x bf16 frag (4 VGPRs)
typedef float v4f __attribute__((ext_vector_type(4)));   // 4 x f32 acc

__device__ inline unsigned short f2bf(float x) {
    unsigned int u = __float_as_uint(x);
    u += 0x7fffu + ((u >> 16) & 1u);
    return (unsigned short)(u >> 16);
}

// agent-scope ops execute at the fabric coherence point (cross-XCD correct).
// RMW reads (fetch_add 0) are guaranteed-fresh there.
__device__ __forceinline__ float fresh_f32(float* p) {
    return __hip_atomic_fetch_add(p, 0.0f, __ATOMIC_RELAXED, __HIP_MEMORY_SCOPE_AGENT);
}
__device__ __forceinline__ int fresh_i32(int* p) {
    return __hip_atomic_fetch_add(p, 0, __ATOMIC_RELAXED, __HIP_MEMORY_SCOPE_AGENT);
}
__device__ __forceinline__ unsigned fresh_u32(unsigned* p) {
    return __hip_atomic_fetch_add(p, 0u, __ATOMIC_RELAXED, __HIP_MEMORY_SCOPE_AGENT);
}
__device__ __forceinline__ void agent_store_f32(float* p, float v) {
    __hip_atomic_store(p, v, __ATOMIC_RELAXED, __HIP_MEMORY_SCOPE_AGENT);
}
__device__ __forceinline__ void agent_store_i32(int* p, int v) {
    __hip_atomic_store(p, v, __ATOMIC_RELAXED, __HIP_MEMORY_SCOPE_AGENT);
}

// ---------------------------------------------------------------------------
// Kernel 1: fused normalize. Wave-per-row.
// ---------------------------------------------------------------------------
__global__ __launch_bounds__(256) void norm_all(const float* __restrict__ supk,
                                                const float* __restrict__ supq,
                                                const float* __restrict__ qry,
                                                unsigned short* __restrict__ Kb,
                                                unsigned short* __restrict__ Qall) {
    int R = blockIdx.x * 4 + (threadIdx.x >> 6);
    int l = threadIdx.x & 63;
    unsigned short* out;
    const float* in;
    float scale;
    if (R < LSUP_PAD) {
        out = Kb + (size_t)R * DIM;
        if (R >= LSUP) {
            #pragma unroll
            for (int k = 0; k < 6; ++k) out[l + 64 * k] = 0;
            return;
        }
        in = supk + (size_t)R * DIM;
        scale = INV_T;
    } else {
        int i = R - LSUP_PAD;
        int img = i / QROWS;
        int r = i - img * QROWS;
        out = Qall + (size_t)i * DIM;
        if (r >= SEQ) {
            #pragma unroll
            for (int k = 0; k < 6; ++k) out[l + 64 * k] = 0;
            return;
        }
        in = (img < NSUP)
            ? supq + ((size_t)img * SEQ + r) * DIM
            : qry  + ((size_t)(img - NSUP) * SEQ + r) * DIM;
        scale = 1.0f;
    }
    float x[6];
    #pragma unroll
    for (int k = 0; k < 6; ++k) x[k] = in[l + 64 * k];
    float s = 0.f;
    #pragma unroll
    for (int k = 0; k < 6; ++k) s += x[k] * x[k];
    #pragma unroll
    for (int m = 1; m < 64; m <<= 1) s += __shfl_xor(s, m);
    float sc = scale / fmaxf(sqrtf(s), 1e-8f);
    #pragma unroll
    for (int k = 0; k < 6; ++k) out[l + 64 * k] = f2bf(x[k] * sc);
}

// ---------------------------------------------------------------------------
// GEMM body: round-6 proven structure. KCC=64, single-buffered, 2 barriers
// per K-step, 128B-per-row line-aligned global_load_lds (round-10 lesson:
// 64B staging granularity doubles FETCH and thrashes L2 lines), XOR swizzle
// slot' = slot ^ (row&7) on pre-swizzled global source + ds_read (rule #21),
// bijective XCD remap. SUPPORT blocks: agent-scope R stores + sdone bump;
// QUERY blocks: plain stores (round-9 lesson: per-dword sc1 write-through
// for 2925 blocks stretched the GEMM ~2x).
// ---------------------------------------------------------------------------
#define MT  128
#define NTP 208
#define KCC 64

__device__ __forceinline__ void gload16(const void* g, void* l) {
    __builtin_amdgcn_global_load_lds(
        (__attribute__((address_space(1))) void*)g,
        (__attribute__((address_space(3))) void*)l, 16, 0, 0);
}

template<int IMG_BASE, int NWG, bool SUPPORT>
__device__ __forceinline__ void gemm_body(
    int gid,
    const unsigned short* __restrict__ Kb,     // [4992][384] bf16, pre /T
    const unsigned short* __restrict__ Qall,   // [100][208][384] bf16
    float* __restrict__ Rall,
    unsigned* counter,
    unsigned short* Asm, unsigned short* Bsm)
{
    int t = threadIdx.x;

    // bijective XCD-aware remap (m204)
    constexpr int qq = NWG >> 3;
    constexpr int rr = NWG & 7;
    int xcd = gid & 7;
    int sub = gid >> 3;
    int L = (xcd < rr ? xcd * (qq + 1) : rr * (qq + 1) + (xcd - rr) * qq) + sub;
    int img = IMG_BASE + L / MTILES;
    int m_base = (L % MTILES) * MT;

    const unsigned short* Qimg = Qall + (size_t)img * (QROWS * DIM);

    int wv = t >> 6;        // wave 0..3
    int l  = t & 63;
    int lo = l & 15;        // MFMA frag row/col index
    int hi = l >> 4;        // k-group
    int mh = (wv >> 1) * 64;   // M-half base row
    int nh = wv & 1;           // N-half

    // staging: each gload16 writes 1024B = 8 rows x 128B, linear LDS dest.
    // lane l covers (row = l>>3, 16B slot = l&7); source slot pre-swizzled.
    int srow = l >> 3;
    int skp  = (l & 7) ^ srow;      // involution within 8-slot row
    const unsigned short* aSrc = Kb   + (size_t)(m_base + wv * 32 + srow) * DIM + skp * 8;
    const unsigned short* bSrc = Qimg + (size_t)srow * DIM + skp * 8;

    v4f acc[4][7];
    #pragma unroll
    for (int m = 0; m < 4; ++m)
        #pragma unroll
        for (int n = 0; n < 7; ++n)
            acc[m][n] = (v4f){0.f, 0.f, 0.f, 0.f};

    for (int kb = 0; kb < DIM; kb += KCC) {
        #pragma unroll
        for (int j = 0; j < 4; ++j)
            gload16(aSrc + (size_t)j * 8 * DIM + kb,
                    Asm + (wv * 32 + j * 8) * KCC);
        #pragma unroll
        for (int jj = 0; jj < 7; ++jj) {
            int j = wv + jj * 4;
            if (j < 26)
                gload16(bSrc + (size_t)j * 8 * DIM + kb,
                        Bsm + j * 8 * KCC);
        }
        __syncthreads();   // drains vmcnt before LDS reads

        const unsigned short* Ar = Asm + (mh + lo) * KCC;
        const unsigned short* Br = Bsm + (nh * 112 + lo) * KCC;
        #pragma unroll
        for (int kk = 0; kk < 2; ++kk) {
            int koff = ((hi + 4 * kk) ^ (lo & 7)) * 8;   // swizzled k-slot
            v8s a0 = *(const v8s*)(Ar + koff);
            v8s a1 = *(const v8s*)(Ar + 16 * KCC + koff);
            v8s a2 = *(const v8s*)(Ar + 32 * KCC + koff);
            v8s a3 = *(const v8s*)(Ar + 48 * KCC + koff);
            #pragma unroll
            for (int n = 0; n < 7; ++n) {
                if (nh == 0 || n < 6) {   // wave-uniform
                    v8s bb = *(const v8s*)(Br + n * 16 * KCC + koff);
                    acc[0][n] = __builtin_amdgcn_mfma_f32_16x16x32_bf16(a0, bb, acc[0][n], 0, 0, 0);
                    acc[1][n] = __builtin_amdgcn_mfma_f32_16x16x32_bf16(a1, bb, acc[1][n], 0, 0, 0);
                    acc[2][n] = __builtin_amdgcn_mfma_f32_16x16x32_bf16(a2, bb, acc[2][n], 0, 0, 0);
                    acc[3][n] = __builtin_amdgcn_mfma_f32_16x16x32_bf16(a3, bb, acc[3][n], 0, 0, 0);
                }
            }
        }
        __syncthreads();
    }

    // epilogue: exp + per-wave column-half sums. C/D: col=lo, row=hi*4+reg.
    float s[4][4];
    #pragma unroll
    for (int m = 0; m < 4; ++m)
        #pragma unroll
        for (int j = 0; j < 4; ++j) s[m][j] = 0.f;
    #pragma unroll
    for (int n = 0; n < 7; ++n) {
        if (nh == 0 || n < 6) {
            bool ok = ((nh * 7 + n) * 16 + lo) < SEQ;
            #pragma unroll
            for (int m = 0; m < 4; ++m)
                #pragma unroll
                for (int j = 0; j < 4; ++j)
                    s[m][j] += ok ? __expf(acc[m][n][j]) : 0.f;
        }
    }
    #pragma unroll
    for (int mm = 1; mm < 16; mm <<= 1) {
        #pragma unroll
        for (int m = 0; m < 4; ++m)
            #pragma unroll
            for (int j = 0; j < 4; ++j)
                s[m][j] += __shfl_xor(s[m][j], mm);
    }
    float* rp = (float*)Asm;   // reuse A LDS: [2][128] row partials
    if (lo == 0) {
        #pragma unroll
        for (int m = 0; m < 4; ++m)
            #pragma unroll
            for (int j = 0; j < 4; ++j)
                rp[nh * 128 + mh + m * 16 + hi * 4 + j] = s[m][j];
    }
    __syncthreads();
    if (t < MT) {
        int gr = m_base + t;
        if (gr < LSUP) {
            float o = rp[t] + rp[128 + t];
            if (img < NSUP && (gr / SEQ) == img) o = 0.f;
            if (SUPPORT)   // write-through so co-resident opt blocks see it
                agent_store_f32(&Rall[(size_t)img * LSUP + gr], o);
            else
                Rall[(size_t)img * LSUP + gr] = o;
        }
    }
    if (SUPPORT) {
        __syncthreads();   // vmcnt(0): sc1 stores acked at coherence point
        if (t == 0)
            __hip_atomic_fetch_add(counter, 1u, __ATOMIC_RELAXED, __HIP_MEMORY_SCOPE_AGENT);
    }
}

// ---------------------------------------------------------------------------
// Kernel 2: MEGA kernel, 3905 blocks x 256.
// ids 0..4: optimizer (class w = id). ids 5..979: support GEMM.
// ids 980..3904: query GEMM. D-exchange: per-producer 128B-padded columns,
// one-shot agent RMW reads, 5 poller lanes, all spins bounded.
// ---------------------------------------------------------------------------
__global__ __launch_bounds__(256, 3) void mega(
    const unsigned short* __restrict__ Kb,
    const unsigned short* __restrict__ Qall,
    float* __restrict__ Rall,
    const int* __restrict__ labels,
    float* __restrict__ Dbuf,       // [16][5][32] floats, pre-zeroed
    int* __restrict__ flags,        // [5*32] ints, pre-zeroed
    unsigned* __restrict__ sdone,   // support-done counter, pre-zeroed
    float* __restrict__ e_out)      // [4900] final e^{v/T}
{
    __shared__ __align__(16) unsigned short Asm[MT * KCC];    // 16 KiB
    __shared__ __align__(16) unsigned short Bsm[NTP * KCC];   // 26 KiB

    int id = blockIdx.x;
    if (id >= NW + NSUPWG) {
        gemm_body<NSUP, NQWG, false>(id - (NW + NSUPWG), Kb, Qall, Rall,
                                     sdone, Asm, Bsm);
        return;
    }
    if (id >= NW) {
        gemm_body<0, NSUPWG, true>(id - NW, Kb, Qall, Rall,
                                   sdone, Asm, Bsm);
        return;
    }

    // ---- optimizer block for class w ----
    float* sh  = (float*)Asm;
    float* red = sh;              // [4][25]
    float* cfs = sh + 100;        // [25]
    float* Dsm = sh + 128;        // [125]
    float* myD = sh + 256;        // [25]
    int*   lsm = (int*)(sh + 288);// [25]

    int w = id;
    int t = threadIdx.x;
    int wave = t >> 6, lane = t & 63;

    // wait for all 975 support blocks (agent RMW; one-time; bounded)
    if (t == 0) {
        unsigned spins = 0;
        while (fresh_u32(sdone) < (unsigned)NSUPWG && ++spins < SPIN_LIMIT)
            __builtin_amdgcn_s_sleep(8);
    }
    __syncthreads();

    // rows r = t + 256k, k<4 (k=3 valid only for t<212); inactive rows -> 0.
    float Rv[4][NSUP];
    #pragma unroll
    for (int b = 0; b < NSUP; ++b) {
        const float* Rb = Rall + (size_t)b * LSUP + w * BLOCK_W;
        Rv[0][b] = Rb[t];
        Rv[1][b] = Rb[t + 256];
        Rv[2][b] = Rb[t + 512];
        Rv[3][b] = (t < BLOCK_W - 768) ? Rb[t + 768] : 0.f;
    }
    if (t < NSUP) lsm[t] = labels[t];

    float e0 = 1.f, e1 = 1.f, e2 = 1.f, e3 = 1.f;
    float v0 = 0.f, v1 = 0.f, v2 = 0.f, v3 = 0.f;

    auto pushD = [&](int step) {
        float part[NSUP];
        #pragma unroll
        for (int b = 0; b < NSUP; ++b)
            part[b] = e0 * Rv[0][b] + e1 * Rv[1][b] + e2 * Rv[2][b] + e3 * Rv[3][b];
        #pragma unroll
        for (int b = 0; b < NSUP; ++b) {
            #pragma unroll
            for (int m = 32; m; m >>= 1) part[b] += __shfl_xor(part[b], m);
        }
        if (lane == 0) {
            #pragma unroll
            for (int b = 0; b < NSUP; ++b) red[wave * NSUP + b] = part[b];
        }
        __syncthreads();
        if (t < NSUP) {
            float s = red[t] + red[NSUP + t] + red[2 * NSUP + t] + red[3 * NSUP + t];
            myD[t] = s;                                    // LDS self-copy
            agent_store_f32(&Dbuf[(step * NW + w) * 32 + t], s);
        }
        __syncthreads();   // vmcnt(0) drain: payload acked at coherence point
        if (t == 0)
            agent_store_i32(&flags[w * 32], step + 1);
    };

    pushD(0);    // e = 1

    for (int s = 0; s < OPT_STEPS; ++s) {
        if (wave == 0) {
            unsigned spins = 0;
            for (;;) {
                int f = (lane < NW) ? fresh_i32(&flags[lane * 32]) : 0x7fffffff;
                if (__all(f >= s + 1)) break;
                if (++spins >= SPIN_LIMIT) break;
                __builtin_amdgcn_s_sleep(1);
            }
        }
        __syncthreads();
        if (t < 125) {
            int wp = t / 25, b = t - wp * 25;
            float dv = (wp == w) ? myD[b]
                                 : fresh_f32(&Dbuf[(s * NW + wp) * 32 + b]);
            Dsm[b * 5 + wp] = dv;
        }
        __syncthreads();
        if (t < NSUP) {
            float Dsum = 0.f, Dw = 1.f;
            #pragma unroll
            for (int ww = 0; ww < NW; ++ww) {
                float d = Dsm[t * 5 + ww];
                Dsum += d;
                if (ww == w) Dw = d;
            }
            cfs[t] = ((Dw / Dsum) - (w == lsm[t] ? 1.f : 0.f)) * (INV_T / 25.f) / Dw;
        }
        __syncthreads();
        float g0 = 0.f, g1 = 0.f, g2 = 0.f, g3 = 0.f;
        #pragma unroll
        for (int b = 0; b < NSUP; ++b) {
            float c = cfs[b];
            g0 += c * Rv[0][b];
            g1 += c * Rv[1][b];
            g2 += c * Rv[2][b];
            g3 += c * Rv[3][b];
        }
        v0 -= LR_F * e0 * g0; e0 = __expf(v0 * INV_T);
        v1 -= LR_F * e1 * g1; e1 = __expf(v1 * INV_T);
        v2 -= LR_F * e2 * g2; e2 = __expf(v2 * INV_T);
        v3 -= LR_F * e3 * g3; e3 = __expf(v3 * INV_T);
        __syncthreads();      // red/Dsm/cfs reuse protection
        if (s + 1 < OPT_STEPS) pushD(s + 1);
    }

    // export e (plain stores; kernel-end writeback covers final_pred)
    float* eo = e_out + w * BLOCK_W;
    eo[t]       = e0;
    eo[t + 256] = e1;
    eo[t + 512] = e2;
    if (t < BLOCK_W - 768) eo[t + 768] = e3;
}

// ---------------------------------------------------------------------------
// Kernel 3: final prediction. 375 blocks (qb*5+w) x 256.
// ---------------------------------------------------------------------------
__global__ __launch_bounds__(256) void final_pred(const float* __restrict__ Rall,
                                                  const float* __restrict__ e_out,
                                                  float* __restrict__ out) {
    __shared__ float ws[4];
    int blk = blockIdx.x;
    int qb = blk / 5, w = blk % 5;
    const float* R  = Rall + (size_t)(NSUP + qb) * LSUP + w * BLOCK_W;
    const float* eb = e_out + w * BLOCK_W;
    int t = threadIdx.x;
    float p = 0.f;
    for (int i = t; i < BLOCK_W; i += 256) p += eb[i] * R[i];
    #pragma unroll
    for (int m = 32; m; m >>= 1) p += __shfl_xor(p, m);
    if ((t & 63) == 0) ws[t >> 6] = p;
    __syncthreads();
    if (t == 0) out[blk] = logf(ws[0] + ws[1] + ws[2] + ws[3]);
}

// ---------------------------------------------------------------------------
extern "C" void kernel_launch(void* const* d_in, const int* in_sizes, int n_in,
                              void* d_out, int out_size, void* d_ws, size_t ws_size,
                              hipStream_t stream) {
    const float* sup_key = (const float*)d_in[0];   // [25,196,384]
    const float* sup_qry = (const float*)d_in[1];   // [25,196,384]
    const float* qry     = (const float*)d_in[2];   // [75,196,384]
    const int*   labels  = (const int*)d_in[3];     // [25]
    float* out = (float*)d_out;                     // [75,5]

    char* ws = (char*)d_ws;
    size_t off = 0;
    auto take = [&](size_t bytes) {
        char* p = ws + off;
        off = (off + bytes + 255) & ~(size_t)255;
        return p;
    };
    unsigned short* Kb   = (unsigned short*)take((size_t)LSUP_PAD * DIM * 2);
    unsigned short* Qall = (unsigned short*)take((size_t)NIMG * QROWS * DIM * 2);
    float*          Rall = (float*)take((size_t)NIMG * LSUP * 4);
    float*          Dbuf = (float*)take((size_t)16 * NW * 32 * 4);   // 10 KiB
    float*          eout = (float*)take((size_t)LSUP * 4);
    int*            fl   = (int*)take(256 * 4);
    int*            flags = fl;                     // [5*32]
    unsigned*       sdone = (unsigned*)(fl + 192);

    hipMemsetAsync(Dbuf, 0, (size_t)16 * NW * 32 * 4, stream);
    hipMemsetAsync(fl, 0, 256 * 4, stream);

    norm_all<<<(LSUP_PAD + NIMG * QROWS) / 4, 256, 0, stream>>>(
        sup_key, sup_qry, qry, Kb, Qall);

    mega<<<NW + NSUPWG + NQWG, 256, 0, stream>>>(
        Kb, Qall, Rall, labels, Dbuf, flags, sdone, eout);

    final_pred<<<NQRY * NW, 256, 0, stream>>>(Rall, eout, out);
}